// Round 15
// baseline (531.858 us; speedup 1.0000x reference)
//
#include <hip/hip_runtime.h>

#define TWO_PI 6.28318530717958647692f

// dims
#define NH 8
#define CH 128     // modes per chunk
#define NCH 2

// workspace offsets (bytes), total ~56.25 MiB (proven-safe)
#define OFF_XM   0ull                        // bf16 [256][128][128]  pre-swizzled units  8 MiB
#define OFF_WTA  (OFF_XM + 8388608ull)       // u32 tiles [CH][8][64][64] pre-swizzled   16 MiB (also Tbuf/G overlay)
#define OFF_WTB  (OFF_WTA + 16777216ull)     // u32 tiles [CH][8][64][64] pre-swizzled   16 MiB
#define OFF_PO   (OFF_WTB + 16777216ull)     // f32: PART [64][16][64][64] / OUTF        16 MiB (shared)
#define OFF_ATTN (OFF_PO + 16777216ull)      // bf16 [16][64][64]
#define WS_TOTAL (OFF_ATTN + 262144ull)

typedef short bf16x8 __attribute__((ext_vector_type(8)));
typedef float f32x4 __attribute__((ext_vector_type(4)));
#define MFMA_B16(a, b, c) __builtin_amdgcn_mfma_f32_16x16x32_bf16(a, b, c, 0, 0, 0)

#define G2L(g, l) __builtin_amdgcn_global_load_lds( \
    (const __attribute__((address_space(1))) void*)(g), \
    (__attribute__((address_space(3))) void*)(l), 16, 0, 0)

__device__ __forceinline__ float bl(unsigned u) { return __uint_as_float(u << 16); }
__device__ __forceinline__ unsigned short f2b(float f) {
    unsigned u = __float_as_uint(f);
    return (unsigned short)((u + 0x7fffu + ((u >> 16) & 1u)) >> 16);
}
__device__ __forceinline__ unsigned pack2(float lo, float hi) {
    return (unsigned)f2b(lo) | ((unsigned)f2b(hi) << 16);
}

// Build doubled-interleaved B-fragment from complex u32 tile Wt[ci][co^ci] (pitch 64).
__device__ __forceinline__ bf16x8 mkfrag(const unsigned* __restrict__ Wt, int co_l, int ri,
                                         int ci0, bool dc) {
    unsigned a0 = Wt[(ci0 + 0) * 64 + (co_l ^ (ci0 + 0))];
    unsigned a1 = Wt[(ci0 + 1) * 64 + (co_l ^ (ci0 + 1))];
    unsigned a2 = Wt[(ci0 + 2) * 64 + (co_l ^ (ci0 + 2))];
    unsigned a3 = Wt[(ci0 + 3) * 64 + (co_l ^ (ci0 + 3))];
    uint4 r;
    if (ri) {
        if (dc) { r.x = 0u; r.y = 0u; r.z = 0u; r.w = 0u; }
        else {
            r.x = (a0 >> 16) | (a0 << 16); r.y = (a1 >> 16) | (a1 << 16);
            r.z = (a2 >> 16) | (a2 << 16); r.w = (a3 >> 16) | (a3 << 16);
        }
    } else {
        r.x = a0 ^ 0x80000000u; r.y = a1 ^ 0x80000000u;
        r.z = a2 ^ 0x80000000u; r.w = a3 ^ 0x80000000u;
    }
    return __builtin_bit_cast(bf16x8, r);
}

// ---------- weight transpose + Parseval prescale -> PRE-SWIZZLED u32 tiles [ml][h][ci*64 + (co^ci)]
__global__ __launch_bounds__(256) void k_transpose2(const float* __restrict__ srcA, unsigned* __restrict__ dstA, int kindA,
                                                    const float* __restrict__ srcB, unsigned* __restrict__ dstB, int kindB,
                                                    int m0) {
    const float* in = (blockIdx.z == 0) ? srcA : srcB;
    unsigned* outp = (blockIdx.z == 0) ? dstA : dstB;
    int kind = (blockIdx.z == 0) ? kindA : kindB;
    __shared__ unsigned T[16][65];
    int tid = threadIdx.x;
    int r0 = blockIdx.x * 64;
    int ci, h;
    if (kind == 2) { h = r0 >> 12; ci = (r0 >> 6) & 63; }   // wo: r = h*4096 + ci*64 + co
    else           { ci = r0 >> 9; h = (r0 >> 6) & 7; }     // wq/wk/wv: r = ci*512 + h*64 + co
    int ml0 = blockIdx.y * 16;
    int u = (m0 + ml0) >> 4;
    const float4* in4 = (const float4*)in;   // 2 complexes per float4
    float fac1 = (kind == 0) ? 1.41421356f : 1.f;
    float facu = (kind == 0) ? (u > 0 ? 0.70710678f : 1.f)
               : (kind == 1) ? (u > 0 ? 0.5f : 1.f) : 1.f;
    #pragma unroll
    for (int p = 0; p < 2; ++p) {
        int f = tid + p * 256;
        int row = f >> 3, mc2 = (f & 7) * 2;
        float4 v = in4[(size_t)(r0 + row) * 128 + ((m0 + ml0) >> 1) + (f & 7)];
        float fac0 = (mc2 > 0) ? fac1 : facu;
        T[mc2][row] = pack2(v.x * fac0, v.y * fac0);
        T[mc2 + 1][row] = pack2(v.z * fac1, v.w * fac1);
    }
    __syncthreads();
    #pragma unroll
    for (int p = 0; p < 4; ++p) {
        int f = tid + p * 256;
        int ml = f >> 6, co = f & 63;
        outp[((size_t)((ml0 + ml) * 8 + h) << 12) + ci * 64 + (co ^ ci)] = T[ml][co];
    }
}

// ---------- rfft stage 1 (y-DFT): T[bs*64+ci][x][v] complex f32
__global__ __launch_bounds__(256) void k_rfft_y(const float* __restrict__ seq,
                                                float2* __restrict__ T) {
    __shared__ float c32[32], s32[32];
    __shared__ float fld[32][33];
    int tid = threadIdx.x;
    int bc = blockIdx.x;   // 0..8191 = bs*64+ci
    if (tid < 32) { float s, c; __sincosf(TWO_PI * tid / 32.0f, &s, &c); c32[tid] = c; s32[tid] = s; }
    float4 v = ((const float4*)(seq + (size_t)bc * 1024))[tid];
    int x = tid >> 3, y4 = (tid & 7) * 4;
    fld[x][y4] = v.x; fld[x][y4 + 1] = v.y; fld[x][y4 + 2] = v.z; fld[x][y4 + 3] = v.w;
    __syncthreads();
    float2* op = T + (size_t)bc * 512;
    #pragma unroll
    for (int p = 0; p < 2; ++p) {
        int e = tid + p * 256;
        int xx = e >> 4, vv = e & 15;
        float sr = 0.f, si = 0.f;
        #pragma unroll
        for (int y = 0; y < 32; ++y) {
            float f = fld[xx][y];
            int ph = (vv * y) & 31;
            sr = fmaf(f, c32[ph], sr);
            si = fmaf(-f, s32[ph], si);
        }
        float2 t; t.x = sr; t.y = si;
        op[e] = t;
    }
}

// ---------- rfft stage 2 (x-DFT) -> XM with PRE-SWIZZLED 16B units: unit' = unit ^ (bs&7)
__global__ __launch_bounds__(256) void k_rfft_x(const float2* __restrict__ T,
                                                unsigned short* __restrict__ XM) {
    __shared__ float c32[32], s32[32];
    __shared__ float2 t[8][512];
    int tid = threadIdx.x;
    int cig = blockIdx.x;   // 0..7
    int bs = blockIdx.y;    // 0..127
    if (tid < 32) { float s, c; __sincosf(TWO_PI * tid / 32.0f, &s, &c); c32[tid] = c; s32[tid] = s; }
    const float4* src = (const float4*)(T + ((size_t)bs * 64 + cig * 8) * 512);
    #pragma unroll
    for (int p = 0; p < 8; ++p) {
        int idx = tid + p * 256;
        float4 w = src[idx];
        int ch = idx >> 8, r2 = idx & 255;
        float2 t0; t0.x = w.x; t0.y = w.y;
        float2 t1; t1.x = w.z; t1.y = w.w;
        t[ch][r2 * 2] = t0; t[ch][r2 * 2 + 1] = t1;
    }
    __syncthreads();
    int u = tid >> 4, vv = tid & 15;
    unsigned outw[8];
    for (int ch = 0; ch < 8; ++ch) {
        float xr = 0.f, xi = 0.f;
        #pragma unroll
        for (int x = 0; x < 32; ++x) {
            float2 tv = t[ch][x * 16 + vv];
            int ph = (u * x) & 31;
            float c = c32[ph], s = s32[ph];
            xr += tv.x * c + tv.y * s;
            xi += tv.y * c - tv.x * s;
        }
        outw[ch] = pack2(xr, xi);
    }
    unsigned short* rowp = XM + ((size_t)tid * 128 + bs) * 128;
    uint4 a, b;
    a.x = outw[0]; a.y = outw[1]; a.z = outw[2]; a.w = outw[3];
    b.x = outw[4]; b.y = outw[5]; b.z = outw[6]; b.w = outw[7];
    int sw = bs & 7;
    *(uint4*)(rowp + ((cig * 2) ^ sw) * 8) = a;
    *(uint4*)(rowp + ((cig * 2 + 1) ^ sw) * 8) = b;
}

// ---------- fused MFMA Q/K modemix + scores: 1024 threads (waves 0-7: b=0, 8-15: b=1), LDS 64KB
__global__ __launch_bounds__(1024) void k_qks(const unsigned short* __restrict__ XM,
                                              const unsigned* __restrict__ WQ,
                                              const unsigned* __restrict__ WK,
                                              float* __restrict__ part, int mbase) {
    __shared__ __align__(16) unsigned char Xs[32768];   // both batches; Qt reuses it
    __shared__ __align__(16) unsigned Wq[4096];         // Kt(b0) reuses it
    __shared__ __align__(16) unsigned Wk[4096];         // Kt(b1) reuses it
    int tid = threadIdx.x;
    int mg = blockIdx.x, h = blockIdx.y;
    int lane = tid & 63, w = tid >> 6;
    int bsel = w >> 3;
    int w8 = w & 7;
    int lr = lane & 15, lg = lane >> 4;
    int wr = w8 & 1, wc = w8 >> 1;
    int sxa = (lr & 7) << 4;
    int ri = lr & 1;
    int rb = bsel * 64;                         // batch row offset in Xs/Qt
    unsigned char* Kbase = bsel ? (unsigned char*)Wk : (unsigned char*)Wq;
    f32x4 zf = {0.f, 0.f, 0.f, 0.f};
    f32x4 sacc[2];
    sacc[0] = zf; sacc[1] = zf;
    for (int mm = 0; mm < 4; ++mm) {
        int ml = mg * 4 + mm;
        int mode = mbase + ml;
        bool dc = (mode == 0);
        __syncthreads();
        {   // async stage full Xs slab (32KB) + Wq + Wk tiles (16KB each)
            const char* xg = (const char*)(XM + (size_t)mode * 128 * 128);
            const char* tq = (const char*)(WQ + ((size_t)(ml * 8 + h) << 12));
            const char* tk = (const char*)(WK + ((size_t)(ml * 8 + h) << 12));
            int off = tid * 16;
            G2L(xg + off, Xs + off);
            G2L(xg + 16384 + off, Xs + 16384 + off);
            G2L(tq + off, (char*)Wq + off);
            G2L(tk + off, (char*)Wk + off);
        }
        __syncthreads();
        f32x4 qa[2][2], ka[2][2];
        {   // Qt = Xs*WQ' ; Kt = Xs*WK'  (results stay in regs)
            #pragma unroll
            for (int m = 0; m < 2; ++m)
                #pragma unroll
                for (int n = 0; n < 2; ++n) { qa[m][n] = zf; ka[m][n] = zf; }
            #pragma unroll
            for (int ks = 0; ks < 4; ++ks) {
                int kb = (ks * 64 + lg * 16) ^ sxa;
                int ci0 = ks * 16 + lg * 4;
                bf16x8 a0 = *(const bf16x8*)(Xs + (rb + wr * 32 + lr) * 256 + kb);
                bf16x8 a1 = *(const bf16x8*)(Xs + (rb + wr * 32 + 16 + lr) * 256 + kb);
                #pragma unroll
                for (int n = 0; n < 2; ++n) {
                    int co_l = wc * 16 + n * 8 + (lr >> 1);
                    bf16x8 bq = mkfrag(Wq, co_l, ri, ci0, dc);
                    bf16x8 bk = mkfrag(Wk, co_l, ri, ci0, dc);
                    qa[0][n] = MFMA_B16(a0, bq, qa[0][n]);
                    qa[1][n] = MFMA_B16(a1, bq, qa[1][n]);
                    ka[0][n] = MFMA_B16(a0, bk, ka[0][n]);
                    ka[1][n] = MFMA_B16(a1, bk, ka[1][n]);
                }
            }
        }
        __syncthreads();   // all Xs/Wq/Wk reads done -> safe to overwrite
        {   // write Qt -> Xs (row rb+..), Kt(b) -> Kbase (local rows)
            #pragma unroll
            for (int m = 0; m < 2; ++m)
                #pragma unroll
                for (int n = 0; n < 2; ++n) {
                    int colb = (wc * 32 + n * 16 + lr) * 2;
                    #pragma unroll
                    for (int r = 0; r < 4; ++r) {
                        int rl = wr * 32 + m * 16 + lg * 4 + r;
                        int swz = (rl & 7) << 4;
                        *(unsigned short*)(Xs + (rb + rl) * 256 + (colb ^ swz)) = f2b(qa[m][n][r]);
                        *(unsigned short*)(Kbase + rl * 256 + (colb ^ swz)) = f2b(ka[m][n][r]);
                    }
                }
        }
        __syncthreads();
        {   // scores: sacc += Qt(64x128) . Kt(64x128)^T  (within own batch)
            #pragma unroll
            for (int ks = 0; ks < 4; ++ks) {
                int kb = (ks * 64 + lg * 16) ^ sxa;
                bf16x8 a0 = *(const bf16x8*)(Xs + (rb + wr * 32 + lr) * 256 + kb);
                bf16x8 a1 = *(const bf16x8*)(Xs + (rb + wr * 32 + 16 + lr) * 256 + kb);
                bf16x8 b0 = *(const bf16x8*)(Kbase + (wc * 16 + lr) * 256 + kb);
                sacc[0] = MFMA_B16(a0, b0, sacc[0]);
                sacc[1] = MFMA_B16(a1, b0, sacc[1]);
            }
        }
    }
    float* pp = part + (((size_t)((mbase >> 2) + mg) * 16 + bsel * 8 + h) << 12);
    #pragma unroll
    for (int m = 0; m < 2; ++m)
        #pragma unroll
        for (int r = 0; r < 4; ++r)
            pp[(wr * 32 + m * 16 + lg * 4 + r) * 64 + wc * 16 + lr] = sacc[m][r];
}

// ---------- reduce partials + inline CPB bias + softmax -> attn bf16
__global__ void k_softmax(const float* __restrict__ part,
                          const float* __restrict__ w1, const float* __restrict__ b1,
                          const float* __restrict__ w2, unsigned short* __restrict__ attnb) {
    int j = threadIdx.x;   // 64
    int i = blockIdx.x;    // 64
    int bh = blockIdx.y;   // 16
    int h = bh & 7;
    float s = 0.f;
    for (int mg = 0; mg < 64; ++mg)
        s += part[(((size_t)mg * 16 + bh) * 64 + i) * 64 + j];
    float dx = (float)((i >> 3) - (j >> 3));
    float dy = (float)((i & 7) - (j & 7));
    float rx = (dx > 0.f ? 1.f : (dx < 0.f ? -1.f : 0.f)) * log1pf(fabsf(dx));
    float ry = (dy > 0.f ? 1.f : (dy < 0.f ? -1.f : 0.f)) * log1pf(fabsf(dy));
    float bias = 0.f;
    for (int l = 0; l < 64; ++l) {
        float hv = fmaxf(rx * w1[l] + ry * w1[64 + l] + b1[l], 0.f);
        bias = fmaf(hv, w2[l * NH + h], bias);
    }
    s = s * (1.0f / 262144.0f) + bias;
    float m = s;
    for (int o = 32; o >= 1; o >>= 1) m = fmaxf(m, __shfl_xor(m, o));
    float e = expf(s - m);
    float t = e;
    for (int o = 32; o >= 1; o >>= 1) t += __shfl_xor(t, o);
    attnb[((size_t)bh * 64 + i) * 64 + j] = f2b(e / t);
}

// ---------- fused MFMA V modemix + attn*V + wo: 1024 threads (waves 0-7: b=0, 8-15: b=1), LDS 80KB
__global__ __launch_bounds__(1024) void k_savo(const unsigned short* __restrict__ XM,
                                               const unsigned* __restrict__ WV,
                                               const unsigned* __restrict__ WO,
                                               const unsigned short* __restrict__ attnb,
                                               float* __restrict__ outf, int mbase) {
    __shared__ __align__(16) unsigned char Xs[32768];   // both batches, live across all h
    __shared__ __align__(16) unsigned Wv[4096];         // then Vt(b0)/Ss(b0)
    __shared__ __align__(16) unsigned Wo[4096];
    __shared__ __align__(16) unsigned char Vt1[16384];  // Vt(b1)/Ss(b1)
    int tid = threadIdx.x;
    int ml = blockIdx.x;
    int mode = mbase + ml;
    bool dc = (mode == 0);
    int lane = tid & 63, w = tid >> 6;
    int bsel = w >> 3;
    int w8 = w & 7;
    int lr = lane & 15, lg = lane >> 4;
    int wr = w8 & 1, wc = w8 >> 1;
    int sxa = (lr & 7) << 4;
    int ri = lr & 1;
    int rb = bsel * 64;
    unsigned char* Vtb = bsel ? Vt1 : (unsigned char*)Wv;   // Vt then Ss slot for this batch
    f32x4 zf = {0.f, 0.f, 0.f, 0.f};
    {   // async stage full Xs slab once (32KB)
        const char* xg = (const char*)(XM + (size_t)mode * 128 * 128);
        int off = tid * 16;
        G2L(xg + off, Xs + off);
        G2L(xg + 16384 + off, Xs + 16384 + off);
    }
    f32x4 oacc[2][2];
    oacc[0][0] = zf; oacc[0][1] = zf; oacc[1][0] = zf; oacc[1][1] = zf;
    for (int h = 0; h < NH; ++h) {
        __syncthreads();   // prior OUT reads of Ss/Wo done -> safe to re-stage
        {   // async stage Wv + Wo tiles (16KB each)
            const char* tv = (const char*)(WV + ((size_t)(ml * 8 + h) << 12));
            const char* to = (const char*)(WO + ((size_t)(ml * 8 + h) << 12));
            int off = tid * 16;
            G2L(tv + off, (char*)Wv + off);
            G2L(to + off, (char*)Wo + off);
        }
        bf16x8 af[2][2];
        #pragma unroll
        for (int m = 0; m < 2; ++m)
            #pragma unroll
            for (int ks = 0; ks < 2; ++ks) {
                int irow = wr * 32 + m * 16 + lr;
                af[m][ks] = *(const bf16x8*)(attnb + (((size_t)(bsel * 8 + h) * 64 + irow) * 64 + ks * 32 + lg * 8));
            }
        __syncthreads();
        f32x4 va[2][2];
        {   // Vtilde = Xs * WV' (regs)
            va[0][0] = zf; va[0][1] = zf; va[1][0] = zf; va[1][1] = zf;
            #pragma unroll
            for (int ks = 0; ks < 4; ++ks) {
                int kb = (ks * 64 + lg * 16) ^ sxa;
                int ci0 = ks * 16 + lg * 4;
                bf16x8 a0 = *(const bf16x8*)(Xs + (rb + wr * 32 + lr) * 256 + kb);
                bf16x8 a1 = *(const bf16x8*)(Xs + (rb + wr * 32 + 16 + lr) * 256 + kb);
                #pragma unroll
                for (int n = 0; n < 2; ++n) {
                    int co_l = wc * 16 + n * 8 + (lr >> 1);
                    bf16x8 bb = mkfrag(Wv, co_l, ri, ci0, dc);
                    va[0][n] = MFMA_B16(a0, bb, va[0][n]);
                    va[1][n] = MFMA_B16(a1, bb, va[1][n]);
                }
            }
        }
        __syncthreads();   // all Wv reads done -> safe to overwrite with Vt(b0)
        {   // write Vt (transposed) into per-batch slot
            #pragma unroll
            for (int m = 0; m < 2; ++m)
                #pragma unroll
                for (int n = 0; n < 2; ++n) {
                    int cp = wc * 32 + n * 16 + lr;
                    int j0 = wr * 32 + m * 16 + lg * 4;
                    uint2 t;
                    t.x = pack2(va[m][n][0], va[m][n][1]);
                    t.y = pack2(va[m][n][2], va[m][n][3]);
                    *(uint2*)(Vtb + cp * 128 + ((j0 * 2) ^ ((cp & 7) << 4))) = t;
                }
        }
        __syncthreads();
        f32x4 sa_[2][2];
        {   // SA = attn * Vtilde (regs)
            sa_[0][0] = zf; sa_[0][1] = zf; sa_[1][0] = zf; sa_[1][1] = zf;
            #pragma unroll
            for (int ks = 0; ks < 2; ++ks) {
                #pragma unroll
                for (int n = 0; n < 2; ++n) {
                    int cp = wc * 32 + n * 16 + lr;
                    bf16x8 bb = *(const bf16x8*)(Vtb + cp * 128 + ((ks * 64 + lg * 16) ^ ((cp & 7) << 4)));
                    sa_[0][n] = MFMA_B16(af[0][ks], bb, sa_[0][n]);
                    sa_[1][n] = MFMA_B16(af[1][ks], bb, sa_[1][n]);
                }
            }
        }
        __syncthreads();   // all Vt reads done -> safe to overwrite with Ss
        {   // write Ss into same per-batch slot
            #pragma unroll
            for (int m = 0; m < 2; ++m)
                #pragma unroll
                for (int n = 0; n < 2; ++n) {
                    int colb = (wc * 32 + n * 16 + lr) * 2;
                    #pragma unroll
                    for (int r = 0; r < 4; ++r) {
                        int rl = wr * 32 + m * 16 + lg * 4 + r;
                        *(unsigned short*)(Vtb + rl * 256 + (colb ^ ((rl & 7) << 4))) = f2b(sa_[m][n][r]);
                    }
                }
        }
        __syncthreads();
        {   // OUT += SA * WO'
            #pragma unroll
            for (int ks = 0; ks < 4; ++ks) {
                int kb = (ks * 64 + lg * 16) ^ sxa;
                int ci0 = ks * 16 + lg * 4;
                bf16x8 a0 = *(const bf16x8*)(Vtb + (wr * 32 + lr) * 256 + kb);
                bf16x8 a1 = *(const bf16x8*)(Vtb + (wr * 32 + 16 + lr) * 256 + kb);
                #pragma unroll
                for (int n = 0; n < 2; ++n) {
                    int co_l = wc * 16 + n * 8 + (lr >> 1);
                    bf16x8 bb = mkfrag(Wo, co_l, ri, ci0, false);
                    oacc[0][n] = MFMA_B16(a0, bb, oacc[0][n]);
                    oacc[1][n] = MFMA_B16(a1, bb, oacc[1][n]);
                }
            }
        }
    }
    #pragma unroll
    for (int m = 0; m < 2; ++m)
        #pragma unroll
        for (int n = 0; n < 2; ++n)
            #pragma unroll
            for (int r = 0; r < 4; ++r) {
                int i = wr * 32 + m * 16 + lg * 4 + r;
                int c2p = wc * 32 + n * 16 + lr;
                outf[((size_t)mode * 128 + rb + i) * 128 + c2p] = oacc[m][n][r];
            }
}

// ---------- irfft stage 1 (v-inverse DFT): G[u][bs][c2][y] complex f32
__global__ __launch_bounds__(256) void k_irfft_v(const float* __restrict__ outf,
                                                 float2* __restrict__ G) {
    __shared__ float c32[32], s32[32];
    __shared__ float2 mf[256][8];
    int tid = threadIdx.x;
    int cg = blockIdx.x;   // 0..7
    int bs = blockIdx.y;   // 0..127
    if (tid < 32) { float s, c; __sincosf(TWO_PI * tid / 32.0f, &s, &c); c32[tid] = c; s32[tid] = s; }
    #pragma unroll
    for (int p = 0; p < 4; ++p) {
        int idx = tid + p * 256;
        int mode = idx >> 2, q = idx & 3;
        float4 v = *(const float4*)(outf + ((size_t)mode * 128 + bs) * 128 + cg * 16 + q * 4);
        float2 t0; t0.x = v.x; t0.y = v.y;
        float2 t1; t1.x = v.z; t1.y = v.w;
        mf[mode][q * 2] = t0; mf[mode][q * 2 + 1] = t1;
    }
    __syncthreads();
    #pragma unroll 1
    for (int p = 0; p < 2; ++p) {
        int e = tid + p * 256;
        int u = e >> 5, y = e & 31;
        #pragma unroll 1
        for (int ch = 0; ch < 8; ++ch) {
            float2 f0 = mf[u * 16][ch];
            float fr0 = f0.x;
            float fi0 = (u == 0) ? 0.f : f0.y;
            float ssr = 0.5f * fr0, ssi = 0.5f * fi0;
            #pragma unroll
            for (int v = 1; v < 16; ++v) {
                float2 f = mf[u * 16 + v][ch];
                int ph = (v * y) & 31;
                float c = c32[ph], s = s32[ph];
                ssr += f.x * c - f.y * s;
                ssi += f.x * s + f.y * c;
            }
            float2 g; g.x = ssr; g.y = ssi;
            G[(((size_t)u * 128 + bs) * 64 + cg * 8 + ch) * 32 + y] = g;
        }
    }
}

// ---------- irfft stage 2 (u-inverse DFT)
__global__ __launch_bounds__(256) void k_irfft_u(const float2* __restrict__ G,
                                                 float* __restrict__ out) {
    __shared__ float c32[32], s32[32];
    __shared__ float2 Gs[16][8][32];    // 32 KB
    int tid = threadIdx.x;
    int cg = blockIdx.x;   // 0..7
    int bs = blockIdx.y;   // 0..127
    if (tid < 32) { float s, c; __sincosf(TWO_PI * tid / 32.0f, &s, &c); c32[tid] = c; s32[tid] = s; }
    #pragma unroll
    for (int p = 0; p < 8; ++p) {
        int idx = tid + p * 256;
        int y2 = idx & 15, ch = (idx >> 4) & 7, u = idx >> 7;
        float4 v = *(const float4*)((const float*)G + ((((size_t)u * 128 + bs) * 64 + cg * 8 + ch) * 32 + y2 * 2) * 2);
        float2 t0; t0.x = v.x; t0.y = v.y;
        float2 t1; t1.x = v.z; t1.y = v.w;
        Gs[u][ch][y2 * 2] = t0; Gs[u][ch][y2 * 2 + 1] = t1;
    }
    __syncthreads();
    #pragma unroll 1
    for (int p = 0; p < 4; ++p) {
        int pos = tid + p * 256;
        int x = pos >> 5, y = pos & 31;
        #pragma unroll 1
        for (int ch = 0; ch < 8; ++ch) {
            float acc = 0.f;
            #pragma unroll
            for (int u = 0; u < 16; ++u) {
                float2 g = Gs[u][ch][y];
                int ph = (u * x) & 31;
                acc += g.x * c32[ph] - g.y * s32[ph];
            }
            out[((size_t)(bs * 64 + cg * 8 + ch)) * 1024 + x * 32 + y] = acc * (1.0f / 512.0f);
        }
    }
}

extern "C" void kernel_launch(void* const* d_in, const int* in_sizes, int n_in,
                              void* d_out, int out_size, void* d_ws, size_t ws_size,
                              hipStream_t stream) {
    (void)in_sizes; (void)n_in; (void)out_size;
    const float* seq = (const float*)d_in[0];
    const float* wq = (const float*)d_in[1];
    const float* wk = (const float*)d_in[2];
    const float* wv = (const float*)d_in[3];
    const float* wo = (const float*)d_in[4];
    const float* cw1 = (const float*)d_in[5];
    const float* cb1 = (const float*)d_in[6];
    const float* cw2 = (const float*)d_in[7];
    float* out = (float*)d_out;
    char* ws = (char*)d_ws;
    if (ws_size < WS_TOTAL) return;

    unsigned short* XM = (unsigned short*)(ws + OFF_XM);
    unsigned* WTA = (unsigned*)(ws + OFF_WTA);
    unsigned* WTB = (unsigned*)(ws + OFF_WTB);
    float2* Tbuf = (float2*)(ws + OFF_WTA);   // 32 MiB overlay on WTA+WTB, dead before transposes
    float2* G = (float2*)(ws + OFF_WTA);      // 32 MiB overlay, used after both k_savo launches
    float* PART = (float*)(ws + OFF_PO);
    float* OUTF = (float*)(ws + OFF_PO);
    unsigned short* ATTNB = (unsigned short*)(ws + OFF_ATTN);

    k_rfft_y<<<dim3(8192), dim3(256), 0, stream>>>(seq, Tbuf);
    k_rfft_x<<<dim3(8, 128), dim3(256), 0, stream>>>(Tbuf, XM);

    for (int c = 0; c < NCH; ++c) {
        int m0 = c * CH;
        k_transpose2<<<dim3(512, CH / 16, 2), dim3(256), 0, stream>>>(wq, WTA, 0, wk, WTB, 0, m0);
        k_qks<<<dim3(CH / 4, NH), dim3(1024), 0, stream>>>(XM, WTA, WTB, PART, m0);
    }
    k_softmax<<<dim3(64, 16), dim3(64), 0, stream>>>(PART, cw1, cb1, cw2, ATTNB);

    for (int c = 0; c < NCH; ++c) {
        int m0 = c * CH;
        k_transpose2<<<dim3(512, CH / 16, 2), dim3(256), 0, stream>>>(wv, WTA, 1, wo, WTB, 2, m0);
        k_savo<<<dim3(CH), dim3(1024), 0, stream>>>(XM, WTA, WTB, ATTNB, OUTF, m0);
    }
    k_irfft_v<<<dim3(8, 128), dim3(256), 0, stream>>>(OUTF, G);
    k_irfft_u<<<dim3(8, 128), dim3(256), 0, stream>>>(G, out);
}

// Round 16
// 320.646 us; speedup vs baseline: 1.6587x; 1.6587x over previous
//
#include <hip/hip_runtime.h>

#define TWO_PI 6.28318530717958647692f

// dims
#define NH 8
#define CH 128     // modes per chunk
#define NCH 2

// workspace offsets (bytes), total ~56.25 MiB (proven-safe)
#define OFF_XM   0ull                        // bf16 [256][128][128]  pre-swizzled units  8 MiB
#define OFF_WTA  (OFF_XM + 8388608ull)       // u32 tiles [CH][8][64][64] pre-swizzled   16 MiB (also Tbuf/G overlay)
#define OFF_WTB  (OFF_WTA + 16777216ull)     // u32 tiles [CH][8][64][64] pre-swizzled   16 MiB
#define OFF_PO   (OFF_WTB + 16777216ull)     // f32: PART [64][16][64][64] / OUTF        16 MiB (shared)
#define OFF_ATTN (OFF_PO + 16777216ull)      // bf16 [16][64][64]
#define WS_TOTAL (OFF_ATTN + 262144ull)

typedef short bf16x8 __attribute__((ext_vector_type(8)));
typedef float f32x4 __attribute__((ext_vector_type(4)));
#define MFMA_B16(a, b, c) __builtin_amdgcn_mfma_f32_16x16x32_bf16(a, b, c, 0, 0, 0)

#define G2L(g, l) __builtin_amdgcn_global_load_lds( \
    (const __attribute__((address_space(1))) void*)(g), \
    (__attribute__((address_space(3))) void*)(l), 16, 0, 0)

__device__ __forceinline__ float bl(unsigned u) { return __uint_as_float(u << 16); }
__device__ __forceinline__ unsigned short f2b(float f) {
    unsigned u = __float_as_uint(f);
    return (unsigned short)((u + 0x7fffu + ((u >> 16) & 1u)) >> 16);
}
__device__ __forceinline__ unsigned pack2(float lo, float hi) {
    return (unsigned)f2b(lo) | ((unsigned)f2b(hi) << 16);
}

// Build doubled-interleaved B-fragment from complex u32 tile Wt[ci][co^ci] (pitch 64).
__device__ __forceinline__ bf16x8 mkfrag(const unsigned* __restrict__ Wt, int co_l, int ri,
                                         int ci0, bool dc) {
    unsigned a0 = Wt[(ci0 + 0) * 64 + (co_l ^ (ci0 + 0))];
    unsigned a1 = Wt[(ci0 + 1) * 64 + (co_l ^ (ci0 + 1))];
    unsigned a2 = Wt[(ci0 + 2) * 64 + (co_l ^ (ci0 + 2))];
    unsigned a3 = Wt[(ci0 + 3) * 64 + (co_l ^ (ci0 + 3))];
    uint4 r;
    if (ri) {
        if (dc) { r.x = 0u; r.y = 0u; r.z = 0u; r.w = 0u; }
        else {
            r.x = (a0 >> 16) | (a0 << 16); r.y = (a1 >> 16) | (a1 << 16);
            r.z = (a2 >> 16) | (a2 << 16); r.w = (a3 >> 16) | (a3 << 16);
        }
    } else {
        r.x = a0 ^ 0x80000000u; r.y = a1 ^ 0x80000000u;
        r.z = a2 ^ 0x80000000u; r.w = a3 ^ 0x80000000u;
    }
    return __builtin_bit_cast(bf16x8, r);
}

// ---------- weight transpose + Parseval prescale -> PRE-SWIZZLED u32 tiles [ml][h][ci*64 + (co^ci)]
__global__ __launch_bounds__(256) void k_transpose2(const float* __restrict__ srcA, unsigned* __restrict__ dstA, int kindA,
                                                    const float* __restrict__ srcB, unsigned* __restrict__ dstB, int kindB,
                                                    int m0) {
    const float* in = (blockIdx.z == 0) ? srcA : srcB;
    unsigned* outp = (blockIdx.z == 0) ? dstA : dstB;
    int kind = (blockIdx.z == 0) ? kindA : kindB;
    __shared__ unsigned T[16][65];
    int tid = threadIdx.x;
    int r0 = blockIdx.x * 64;
    int ci, h;
    if (kind == 2) { h = r0 >> 12; ci = (r0 >> 6) & 63; }   // wo: r = h*4096 + ci*64 + co
    else           { ci = r0 >> 9; h = (r0 >> 6) & 7; }     // wq/wk/wv: r = ci*512 + h*64 + co
    int ml0 = blockIdx.y * 16;
    int u = (m0 + ml0) >> 4;
    const float4* in4 = (const float4*)in;   // 2 complexes per float4
    float fac1 = (kind == 0) ? 1.41421356f : 1.f;
    float facu = (kind == 0) ? (u > 0 ? 0.70710678f : 1.f)
               : (kind == 1) ? (u > 0 ? 0.5f : 1.f) : 1.f;
    #pragma unroll
    for (int p = 0; p < 2; ++p) {
        int f = tid + p * 256;
        int row = f >> 3, mc2 = (f & 7) * 2;
        float4 v = in4[(size_t)(r0 + row) * 128 + ((m0 + ml0) >> 1) + (f & 7)];
        float fac0 = (mc2 > 0) ? fac1 : facu;
        T[mc2][row] = pack2(v.x * fac0, v.y * fac0);
        T[mc2 + 1][row] = pack2(v.z * fac1, v.w * fac1);
    }
    __syncthreads();
    #pragma unroll
    for (int p = 0; p < 4; ++p) {
        int f = tid + p * 256;
        int ml = f >> 6, co = f & 63;
        outp[((size_t)((ml0 + ml) * 8 + h) << 12) + ci * 64 + (co ^ ci)] = T[ml][co];
    }
}

// ---------- rfft stage 1 (y-DFT): T[bs*64+ci][x][v] complex f32
__global__ __launch_bounds__(256) void k_rfft_y(const float* __restrict__ seq,
                                                float2* __restrict__ T) {
    __shared__ float c32[32], s32[32];
    __shared__ float fld[32][33];
    int tid = threadIdx.x;
    int bc = blockIdx.x;   // 0..8191 = bs*64+ci
    if (tid < 32) { float s, c; __sincosf(TWO_PI * tid / 32.0f, &s, &c); c32[tid] = c; s32[tid] = s; }
    float4 v = ((const float4*)(seq + (size_t)bc * 1024))[tid];
    int x = tid >> 3, y4 = (tid & 7) * 4;
    fld[x][y4] = v.x; fld[x][y4 + 1] = v.y; fld[x][y4 + 2] = v.z; fld[x][y4 + 3] = v.w;
    __syncthreads();
    float2* op = T + (size_t)bc * 512;
    #pragma unroll
    for (int p = 0; p < 2; ++p) {
        int e = tid + p * 256;
        int xx = e >> 4, vv = e & 15;
        float sr = 0.f, si = 0.f;
        #pragma unroll
        for (int y = 0; y < 32; ++y) {
            float f = fld[xx][y];
            int ph = (vv * y) & 31;
            sr = fmaf(f, c32[ph], sr);
            si = fmaf(-f, s32[ph], si);
        }
        float2 t; t.x = sr; t.y = si;
        op[e] = t;
    }
}

// ---------- rfft stage 2 (x-DFT) -> XM with PRE-SWIZZLED 16B units: unit' = unit ^ (bs&7)
__global__ __launch_bounds__(256) void k_rfft_x(const float2* __restrict__ T,
                                                unsigned short* __restrict__ XM) {
    __shared__ float c32[32], s32[32];
    __shared__ float2 t[8][512];
    int tid = threadIdx.x;
    int cig = blockIdx.x;   // 0..7
    int bs = blockIdx.y;    // 0..127
    if (tid < 32) { float s, c; __sincosf(TWO_PI * tid / 32.0f, &s, &c); c32[tid] = c; s32[tid] = s; }
    const float4* src = (const float4*)(T + ((size_t)bs * 64 + cig * 8) * 512);
    #pragma unroll
    for (int p = 0; p < 8; ++p) {
        int idx = tid + p * 256;
        float4 w = src[idx];
        int ch = idx >> 8, r2 = idx & 255;
        float2 t0; t0.x = w.x; t0.y = w.y;
        float2 t1; t1.x = w.z; t1.y = w.w;
        t[ch][r2 * 2] = t0; t[ch][r2 * 2 + 1] = t1;
    }
    __syncthreads();
    int u = tid >> 4, vv = tid & 15;
    unsigned outw[8];
    for (int ch = 0; ch < 8; ++ch) {
        float xr = 0.f, xi = 0.f;
        #pragma unroll
        for (int x = 0; x < 32; ++x) {
            float2 tv = t[ch][x * 16 + vv];
            int ph = (u * x) & 31;
            float c = c32[ph], s = s32[ph];
            xr += tv.x * c + tv.y * s;
            xi += tv.y * c - tv.x * s;
        }
        outw[ch] = pack2(xr, xi);
    }
    unsigned short* rowp = XM + ((size_t)tid * 128 + bs) * 128;
    uint4 a, b;
    a.x = outw[0]; a.y = outw[1]; a.z = outw[2]; a.w = outw[3];
    b.x = outw[4]; b.y = outw[5]; b.z = outw[6]; b.w = outw[7];
    int sw = bs & 7;
    *(uint4*)(rowp + ((cig * 2) ^ sw) * 8) = a;
    *(uint4*)(rowp + ((cig * 2 + 1) ^ sw) * 8) = b;
}

// ---------- fused MFMA Q/K modemix + scores: 512 threads, LDS 48KB, async staging
__global__ __launch_bounds__(512) void k_qks(const unsigned short* __restrict__ XM,
                                             const unsigned* __restrict__ WQ,
                                             const unsigned* __restrict__ WK,
                                             float* __restrict__ part, int mbase) {
    __shared__ __align__(16) unsigned char Xs[16384];
    __shared__ __align__(16) unsigned Wq[4096];
    __shared__ __align__(16) unsigned Wk[4096];
    unsigned char* Qs = Xs;                     // reused after Qt/Kt compute
    unsigned char* Ks = (unsigned char*)Wq;     // reused after Qt/Kt compute
    int tid = threadIdx.x;
    int mg = blockIdx.x, h = blockIdx.y, b = blockIdx.z;
    int lane = tid & 63, w = tid >> 6;
    int lr = lane & 15, lg = lane >> 4;
    int wr = w & 1, wc = w >> 1;
    int sxa = (lr & 7) << 4;
    int ri = lr & 1;
    f32x4 zf = {0.f, 0.f, 0.f, 0.f};
    f32x4 sacc[2];
    sacc[0] = zf; sacc[1] = zf;
    for (int mm = 0; mm < 4; ++mm) {
        int ml = mg * 4 + mm;
        int mode = mbase + ml;
        bool dc = (mode == 0);
        __syncthreads();
        {   // async stage Xs + Wq + Wk (all pre-swizzled in global; linear copies)
            const char* xg = (const char*)(XM + ((size_t)mode * 128 + b * 64) * 128);
            const char* tq = (const char*)(WQ + ((size_t)(ml * 8 + h) << 12));
            const char* tk = (const char*)(WK + ((size_t)(ml * 8 + h) << 12));
            #pragma unroll
            for (int p = 0; p < 2; ++p) {
                int off = (tid + p * 512) * 16;
                G2L(xg + off, Xs + off);
                G2L(tq + off, (char*)Wq + off);
                G2L(tk + off, (char*)Wk + off);
            }
        }
        __syncthreads();
        f32x4 qa[2][2], ka[2][2];
        {   // Qt = Xs*WQ' ; Kt = Xs*WK'  (results stay in regs)
            #pragma unroll
            for (int m = 0; m < 2; ++m)
                #pragma unroll
                for (int n = 0; n < 2; ++n) { qa[m][n] = zf; ka[m][n] = zf; }
            #pragma unroll
            for (int ks = 0; ks < 4; ++ks) {
                int kb = (ks * 64 + lg * 16) ^ sxa;
                int ci0 = ks * 16 + lg * 4;
                bf16x8 a0 = *(const bf16x8*)(Xs + (wr * 32 + lr) * 256 + kb);
                bf16x8 a1 = *(const bf16x8*)(Xs + (wr * 32 + 16 + lr) * 256 + kb);
                #pragma unroll
                for (int n = 0; n < 2; ++n) {
                    int co_l = wc * 16 + n * 8 + (lr >> 1);
                    bf16x8 bq = mkfrag(Wq, co_l, ri, ci0, dc);
                    bf16x8 bk = mkfrag(Wk, co_l, ri, ci0, dc);
                    qa[0][n] = MFMA_B16(a0, bq, qa[0][n]);
                    qa[1][n] = MFMA_B16(a1, bq, qa[1][n]);
                    ka[0][n] = MFMA_B16(a0, bk, ka[0][n]);
                    ka[1][n] = MFMA_B16(a1, bk, ka[1][n]);
                }
            }
        }
        __syncthreads();   // all Xs/Wq/Wk reads done -> safe to overwrite
        {   // write Qt -> Qs(=Xs), Kt -> Ks(=Wq)
            #pragma unroll
            for (int m = 0; m < 2; ++m)
                #pragma unroll
                for (int n = 0; n < 2; ++n) {
                    int colb = (wc * 32 + n * 16 + lr) * 2;
                    #pragma unroll
                    for (int r = 0; r < 4; ++r) {
                        int row = wr * 32 + m * 16 + lg * 4 + r;
                        int swz = (row & 7) << 4;
                        *(unsigned short*)(Qs + row * 256 + (colb ^ swz)) = f2b(qa[m][n][r]);
                        *(unsigned short*)(Ks + row * 256 + (colb ^ swz)) = f2b(ka[m][n][r]);
                    }
                }
        }
        __syncthreads();
        {   // scores: sacc += Qt(64x128) . Kt(64x128)^T
            #pragma unroll
            for (int ks = 0; ks < 4; ++ks) {
                int kb = (ks * 64 + lg * 16) ^ sxa;
                bf16x8 a0 = *(const bf16x8*)(Qs + (wr * 32 + lr) * 256 + kb);
                bf16x8 a1 = *(const bf16x8*)(Qs + (wr * 32 + 16 + lr) * 256 + kb);
                bf16x8 b0 = *(const bf16x8*)(Ks + (wc * 16 + lr) * 256 + kb);
                sacc[0] = MFMA_B16(a0, b0, sacc[0]);
                sacc[1] = MFMA_B16(a1, b0, sacc[1]);
            }
        }
    }
    float* pp = part + (((size_t)((mbase >> 2) + mg) * 16 + b * 8 + h) << 12);
    #pragma unroll
    for (int m = 0; m < 2; ++m)
        #pragma unroll
        for (int r = 0; r < 4; ++r)
            pp[(wr * 32 + m * 16 + lg * 4 + r) * 64 + wc * 16 + lr] = sacc[m][r];
}

// ---------- reduce partials + inline CPB bias + softmax -> attn bf16
__global__ void k_softmax(const float* __restrict__ part,
                          const float* __restrict__ w1, const float* __restrict__ b1,
                          const float* __restrict__ w2, unsigned short* __restrict__ attnb) {
    int j = threadIdx.x;   // 64
    int i = blockIdx.x;    // 64
    int bh = blockIdx.y;   // 16
    int h = bh & 7;
    float s = 0.f;
    for (int mg = 0; mg < 64; ++mg)
        s += part[(((size_t)mg * 16 + bh) * 64 + i) * 64 + j];
    float dx = (float)((i >> 3) - (j >> 3));
    float dy = (float)((i & 7) - (j & 7));
    float rx = (dx > 0.f ? 1.f : (dx < 0.f ? -1.f : 0.f)) * log1pf(fabsf(dx));
    float ry = (dy > 0.f ? 1.f : (dy < 0.f ? -1.f : 0.f)) * log1pf(fabsf(dy));
    float bias = 0.f;
    for (int l = 0; l < 64; ++l) {
        float hv = fmaxf(rx * w1[l] + ry * w1[64 + l] + b1[l], 0.f);
        bias = fmaf(hv, w2[l * NH + h], bias);
    }
    s = s * (1.0f / 262144.0f) + bias;
    float m = s;
    for (int o = 32; o >= 1; o >>= 1) m = fmaxf(m, __shfl_xor(m, o));
    float e = expf(s - m);
    float t = e;
    for (int o = 32; o >= 1; o >>= 1) t += __shfl_xor(t, o);
    attnb[((size_t)bh * 64 + i) * 64 + j] = f2b(e / t);
}

// ---------- fused MFMA V modemix + attn*V + wo: 512 threads, LDS 48KB, async staging
__global__ __launch_bounds__(512) void k_savo(const unsigned short* __restrict__ XM,
                                              const unsigned* __restrict__ WV,
                                              const unsigned* __restrict__ WO,
                                              const unsigned short* __restrict__ attnb,
                                              float* __restrict__ outf, int mbase) {
    __shared__ __align__(16) unsigned char Xs[16384];
    __shared__ __align__(16) unsigned Wv[4096];   // then Vt, then Ss
    __shared__ __align__(16) unsigned Wo[4096];
    unsigned char* Vt = (unsigned char*)Wv;
    unsigned char* Ss = (unsigned char*)Wv;
    int tid = threadIdx.x;
    int ml = blockIdx.x, b = blockIdx.y;
    int mode = mbase + ml;
    bool dc = (mode == 0);
    int lane = tid & 63, w = tid >> 6;
    int lr = lane & 15, lg = lane >> 4;
    int wr = w & 1, wc = w >> 1;
    int sxa = (lr & 7) << 4;
    int ri = lr & 1;
    f32x4 zf = {0.f, 0.f, 0.f, 0.f};
    {   // async stage Xs once (pre-swizzled, linear)
        const char* xg = (const char*)(XM + ((size_t)mode * 128 + b * 64) * 128);
        #pragma unroll
        for (int p = 0; p < 2; ++p) {
            int off = (tid + p * 512) * 16;
            G2L(xg + off, Xs + off);
        }
    }
    f32x4 oacc[2][2];
    oacc[0][0] = zf; oacc[0][1] = zf; oacc[1][0] = zf; oacc[1][1] = zf;
    for (int h = 0; h < NH; ++h) {
        __syncthreads();   // prior OUT reads of Ss/Wo done -> safe to re-stage
        {   // async stage Wv + Wo tiles (pre-swizzled, linear)
            const char* tv = (const char*)(WV + ((size_t)(ml * 8 + h) << 12));
            const char* to = (const char*)(WO + ((size_t)(ml * 8 + h) << 12));
            #pragma unroll
            for (int p = 0; p < 2; ++p) {
                int off = (tid + p * 512) * 16;
                G2L(tv + off, (char*)Wv + off);
                G2L(to + off, (char*)Wo + off);
            }
        }
        bf16x8 af[2][2];
        #pragma unroll
        for (int m = 0; m < 2; ++m)
            #pragma unroll
            for (int ks = 0; ks < 2; ++ks) {
                int irow = wr * 32 + m * 16 + lr;
                af[m][ks] = *(const bf16x8*)(attnb + (((size_t)(b * 8 + h) * 64 + irow) * 64 + ks * 32 + lg * 8));
            }
        __syncthreads();
        f32x4 va[2][2];
        {   // Vtilde = Xs * WV' (regs)
            va[0][0] = zf; va[0][1] = zf; va[1][0] = zf; va[1][1] = zf;
            #pragma unroll
            for (int ks = 0; ks < 4; ++ks) {
                int kb = (ks * 64 + lg * 16) ^ sxa;
                int ci0 = ks * 16 + lg * 4;
                bf16x8 a0 = *(const bf16x8*)(Xs + (wr * 32 + lr) * 256 + kb);
                bf16x8 a1 = *(const bf16x8*)(Xs + (wr * 32 + 16 + lr) * 256 + kb);
                #pragma unroll
                for (int n = 0; n < 2; ++n) {
                    int co_l = wc * 16 + n * 8 + (lr >> 1);
                    bf16x8 bb = mkfrag(Wv, co_l, ri, ci0, dc);
                    va[0][n] = MFMA_B16(a0, bb, va[0][n]);
                    va[1][n] = MFMA_B16(a1, bb, va[1][n]);
                }
            }
        }
        __syncthreads();   // all Wv reads done -> safe to overwrite with Vt
        {   // write Vt (transposed) into Wv slot
            #pragma unroll
            for (int m = 0; m < 2; ++m)
                #pragma unroll
                for (int n = 0; n < 2; ++n) {
                    int cp = wc * 32 + n * 16 + lr;
                    int j0 = wr * 32 + m * 16 + lg * 4;
                    uint2 t;
                    t.x = pack2(va[m][n][0], va[m][n][1]);
                    t.y = pack2(va[m][n][2], va[m][n][3]);
                    *(uint2*)(Vt + cp * 128 + ((j0 * 2) ^ ((cp & 7) << 4))) = t;
                }
        }
        __syncthreads();
        f32x4 sa_[2][2];
        {   // SA = attn * Vtilde (regs)
            sa_[0][0] = zf; sa_[0][1] = zf; sa_[1][0] = zf; sa_[1][1] = zf;
            #pragma unroll
            for (int ks = 0; ks < 2; ++ks) {
                #pragma unroll
                for (int n = 0; n < 2; ++n) {
                    int cp = wc * 32 + n * 16 + lr;
                    bf16x8 bb = *(const bf16x8*)(Vt + cp * 128 + ((ks * 64 + lg * 16) ^ ((cp & 7) << 4)));
                    sa_[0][n] = MFMA_B16(af[0][ks], bb, sa_[0][n]);
                    sa_[1][n] = MFMA_B16(af[1][ks], bb, sa_[1][n]);
                }
            }
        }
        __syncthreads();   // all Vt reads done -> safe to overwrite with Ss
        {   // write Ss into same slot
            #pragma unroll
            for (int m = 0; m < 2; ++m)
                #pragma unroll
                for (int n = 0; n < 2; ++n) {
                    int colb = (wc * 32 + n * 16 + lr) * 2;
                    #pragma unroll
                    for (int r = 0; r < 4; ++r) {
                        int row = wr * 32 + m * 16 + lg * 4 + r;
                        *(unsigned short*)(Ss + row * 256 + (colb ^ ((row & 7) << 4))) = f2b(sa_[m][n][r]);
                    }
                }
        }
        __syncthreads();
        {   // OUT += SA * WO'
            #pragma unroll
            for (int ks = 0; ks < 4; ++ks) {
                int kb = (ks * 64 + lg * 16) ^ sxa;
                int ci0 = ks * 16 + lg * 4;
                bf16x8 a0 = *(const bf16x8*)(Ss + (wr * 32 + lr) * 256 + kb);
                bf16x8 a1 = *(const bf16x8*)(Ss + (wr * 32 + 16 + lr) * 256 + kb);
                #pragma unroll
                for (int n = 0; n < 2; ++n) {
                    int co_l = wc * 16 + n * 8 + (lr >> 1);
                    bf16x8 bb = mkfrag(Wo, co_l, ri, ci0, false);
                    oacc[0][n] = MFMA_B16(a0, bb, oacc[0][n]);
                    oacc[1][n] = MFMA_B16(a1, bb, oacc[1][n]);
                }
            }
        }
    }
    #pragma unroll
    for (int m = 0; m < 2; ++m)
        #pragma unroll
        for (int n = 0; n < 2; ++n)
            #pragma unroll
            for (int r = 0; r < 4; ++r) {
                int i = wr * 32 + m * 16 + lg * 4 + r;
                int c2p = wc * 32 + n * 16 + lr;
                outf[((size_t)mode * 128 + b * 64 + i) * 128 + c2p] = oacc[m][n][r];
            }
}

// ---------- irfft stage 1 (v-inverse DFT): G[u][bs][c2][y] complex f32
__global__ __launch_bounds__(256) void k_irfft_v(const float* __restrict__ outf,
                                                 float2* __restrict__ G) {
    __shared__ float c32[32], s32[32];
    __shared__ float2 mf[256][8];
    int tid = threadIdx.x;
    int cg = blockIdx.x;   // 0..7
    int bs = blockIdx.y;   // 0..127
    if (tid < 32) { float s, c; __sincosf(TWO_PI * tid / 32.0f, &s, &c); c32[tid] = c; s32[tid] = s; }
    #pragma unroll
    for (int p = 0; p < 4; ++p) {
        int idx = tid + p * 256;
        int mode = idx >> 2, q = idx & 3;
        float4 v = *(const float4*)(outf + ((size_t)mode * 128 + bs) * 128 + cg * 16 + q * 4);
        float2 t0; t0.x = v.x; t0.y = v.y;
        float2 t1; t1.x = v.z; t1.y = v.w;
        mf[mode][q * 2] = t0; mf[mode][q * 2 + 1] = t1;
    }
    __syncthreads();
    #pragma unroll 1
    for (int p = 0; p < 2; ++p) {
        int e = tid + p * 256;
        int u = e >> 5, y = e & 31;
        #pragma unroll 1
        for (int ch = 0; ch < 8; ++ch) {
            float2 f0 = mf[u * 16][ch];
            float fr0 = f0.x;
            float fi0 = (u == 0) ? 0.f : f0.y;
            float ssr = 0.5f * fr0, ssi = 0.5f * fi0;
            #pragma unroll
            for (int v = 1; v < 16; ++v) {
                float2 f = mf[u * 16 + v][ch];
                int ph = (v * y) & 31;
                float c = c32[ph], s = s32[ph];
                ssr += f.x * c - f.y * s;
                ssi += f.x * s + f.y * c;
            }
            float2 g; g.x = ssr; g.y = ssi;
            G[(((size_t)u * 128 + bs) * 64 + cg * 8 + ch) * 32 + y] = g;
        }
    }
}

// ---------- irfft stage 2 (u-inverse DFT)
__global__ __launch_bounds__(256) void k_irfft_u(const float2* __restrict__ G,
                                                 float* __restrict__ out) {
    __shared__ float c32[32], s32[32];
    __shared__ float2 Gs[16][8][32];    // 32 KB
    int tid = threadIdx.x;
    int cg = blockIdx.x;   // 0..7
    int bs = blockIdx.y;   // 0..127
    if (tid < 32) { float s, c; __sincosf(TWO_PI * tid / 32.0f, &s, &c); c32[tid] = c; s32[tid] = s; }
    #pragma unroll
    for (int p = 0; p < 8; ++p) {
        int idx = tid + p * 256;
        int y2 = idx & 15, ch = (idx >> 4) & 7, u = idx >> 7;
        float4 v = *(const float4*)((const float*)G + ((((size_t)u * 128 + bs) * 64 + cg * 8 + ch) * 32 + y2 * 2) * 2);
        float2 t0; t0.x = v.x; t0.y = v.y;
        float2 t1; t1.x = v.z; t1.y = v.w;
        Gs[u][ch][y2 * 2] = t0; Gs[u][ch][y2 * 2 + 1] = t1;
    }
    __syncthreads();
    #pragma unroll 1
    for (int p = 0; p < 4; ++p) {
        int pos = tid + p * 256;
        int x = pos >> 5, y = pos & 31;
        #pragma unroll 1
        for (int ch = 0; ch < 8; ++ch) {
            float acc = 0.f;
            #pragma unroll
            for (int u = 0; u < 16; ++u) {
                float2 g = Gs[u][ch][y];
                int ph = (u * x) & 31;
                acc += g.x * c32[ph] - g.y * s32[ph];
            }
            out[((size_t)(bs * 64 + cg * 8 + ch)) * 1024 + x * 32 + y] = acc * (1.0f / 512.0f);
        }
    }
}

extern "C" void kernel_launch(void* const* d_in, const int* in_sizes, int n_in,
                              void* d_out, int out_size, void* d_ws, size_t ws_size,
                              hipStream_t stream) {
    (void)in_sizes; (void)n_in; (void)out_size;
    const float* seq = (const float*)d_in[0];
    const float* wq = (const float*)d_in[1];
    const float* wk = (const float*)d_in[2];
    const float* wv = (const float*)d_in[3];
    const float* wo = (const float*)d_in[4];
    const float* cw1 = (const float*)d_in[5];
    const float* cb1 = (const float*)d_in[6];
    const float* cw2 = (const float*)d_in[7];
    float* out = (float*)d_out;
    char* ws = (char*)d_ws;
    if (ws_size < WS_TOTAL) return;

    unsigned short* XM = (unsigned short*)(ws + OFF_XM);
    unsigned* WTA = (unsigned*)(ws + OFF_WTA);
    unsigned* WTB = (unsigned*)(ws + OFF_WTB);
    float2* Tbuf = (float2*)(ws + OFF_WTA);   // 32 MiB overlay on WTA+WTB, dead before transposes
    float2* G = (float2*)(ws + OFF_WTA);      // 32 MiB overlay, used after both k_savo launches
    float* PART = (float*)(ws + OFF_PO);
    float* OUTF = (float*)(ws + OFF_PO);
    unsigned short* ATTNB = (unsigned short*)(ws + OFF_ATTN);

    k_rfft_y<<<dim3(8192), dim3(256), 0, stream>>>(seq, Tbuf);
    k_rfft_x<<<dim3(8, 128), dim3(256), 0, stream>>>(Tbuf, XM);

    for (int c = 0; c < NCH; ++c) {
        int m0 = c * CH;
        k_transpose2<<<dim3(512, CH / 16, 2), dim3(256), 0, stream>>>(wq, WTA, 0, wk, WTB, 0, m0);
        k_qks<<<dim3(CH / 4, NH, 2), dim3(512), 0, stream>>>(XM, WTA, WTB, PART, m0);
    }
    k_softmax<<<dim3(64, 16), dim3(64), 0, stream>>>(PART, cw1, cb1, cw2, ATTNB);

    for (int c = 0; c < NCH; ++c) {
        int m0 = c * CH;
        k_transpose2<<<dim3(512, CH / 16, 2), dim3(256), 0, stream>>>(wv, WTA, 1, wo, WTB, 2, m0);
        k_savo<<<dim3(CH, 2), dim3(512), 0, stream>>>(XM, WTA, WTB, ATTNB, OUTF, m0);
    }
    k_irfft_v<<<dim3(8, 128), dim3(256), 0, stream>>>(OUTF, G);
    k_irfft_u<<<dim3(8, 128), dim3(256), 0, stream>>>(G, out);
}